// Round 10
// baseline (242.294 us; speedup 1.0000x reference)
//
// v8: revert coop (R9 failed: coop launch doesn't execute under graph capture).
// 4 dispatches: convert | gatebin | gemm(BK=32 double-buffer, XCD-pinned) | combine.
// Dbuf rationale: R8 proved A/B loads are L2-hits (FETCH~34MB); BK=32 keeps
// LDS at 24KB total -> 6 blocks/CU retained (R5's occupancy loss removed),
// and the 1-iter prefetch slack now covers L2 latency (~200-300cy).
#include <hip/hip_runtime.h>
#include <hip/hip_fp16.h>
#include <stdint.h>

#define NTOK 8192   // B*T
#define D 1024
#define E 8
#define BM 128
#define BN 64
#define BK 32
#define NKT (D / BK)      // 32
#define ABUF (BM * BK)    // 4096 elem (8 KB)
#define BBUF (BN * BK)    // 2048 elem (4 KB)
#define GEMM_GRID ((NTOK / BM) * (D / BN) * E)   // 8192

typedef __attribute__((ext_vector_type(8))) short short8;
typedef __attribute__((ext_vector_type(4))) float f32x4;

// fp32 -> bf16 bits, round-to-nearest-even
__device__ __forceinline__ ushort f2bf(float f) {
  uint32_t x = __float_as_uint(f);
  x += 0x7FFFu + ((x >> 16) & 1u);
  return (ushort)(x >> 16);
}

__device__ __forceinline__ ushort f2h(float f) {
  union { __half h; ushort u; } cv;
  cv.h = __float2half(f);
  return cv.u;
}
__device__ __forceinline__ float h2f(ushort u) {
  union { __half h; ushort u; } cv;
  cv.u = u;
  return __half2float(cv.h);
}

// Convert expert_W -> bf16, delta -> bf16, zero cnt. No out-zero needed:
// the packed-halves epilogue writes every byte of out exactly once.
#define NW4 2097152   // E*D*D/4
#define ND4 2097152   // NTOK*D/4
__global__ __launch_bounds__(256) void convert_kernel(
    const float* __restrict__ expert_W, const float* __restrict__ delta,
    ushort* __restrict__ Wb, ushort* __restrict__ Db, int* __restrict__ cnt) {
  int i = blockIdx.x * 256 + threadIdx.x;
  if (i < E) cnt[i] = 0;
  if (i < NW4) {
    float4 v = ((const float4*)expert_W)[i];
    ushort4 u; u.x = f2bf(v.x); u.y = f2bf(v.y); u.z = f2bf(v.z); u.w = f2bf(v.w);
    ((ushort4*)Wb)[i] = u;
  } else {
    int j = i - NW4;
    float4 v = ((const float4*)delta)[j];
    ushort4 u; u.x = f2bf(v.x); u.y = f2bf(v.y); u.z = f2bf(v.z); u.w = f2bf(v.w);
    ((ushort4*)Db)[j] = u;
  }
}

// Fused gate + bin: wave per token (4 tokens/block); top-2 + softmax; then
// block-level counting-append into per-expert lists (8 global atomics/block).
// List entry encodes rank in bit 31 (rank0 -> low f16 half of the out word,
// rank1 -> high half).
__global__ __launch_bounds__(256) void gatebin_kernel(
    const float* __restrict__ x, const float* __restrict__ gW,
    const float* __restrict__ gb, int* __restrict__ cnt,
    int* __restrict__ list, float* __restrict__ wlist) {
  int wv = threadIdx.x >> 6;
  int lane = threadIdx.x & 63;
  int tid = threadIdx.x;
  int t = blockIdx.x * 4 + wv;

  const float4* xr = (const float4*)(x + (size_t)t * D) + lane * 4;
  float acc[E];
#pragma unroll
  for (int e = 0; e < E; ++e) acc[e] = 0.f;
#pragma unroll
  for (int qq = 0; qq < 4; ++qq) {
    float4 xv = xr[qq];
#pragma unroll
    for (int e = 0; e < E; ++e) {
      float4 wvv = ((const float4*)(gW + e * D))[lane * 4 + qq];
      acc[e] += xv.x * wvv.x + xv.y * wvv.y + xv.z * wvv.z + xv.w * wvv.w;
    }
  }
#pragma unroll
  for (int e = 0; e < E; ++e) {
    float v = acc[e];
#pragma unroll
    for (int off = 32; off > 0; off >>= 1) v += __shfl_xor(v, off, 64);
    acc[e] = v;
  }

  __shared__ int sIdx[4];      // packed i0 | i1<<16 per wave
  __shared__ float2 sW[4];
  __shared__ int hist[E];
  __shared__ int base[E];
  __shared__ int rofs[4][2];   // within-block rank offsets

  if (lane == 0) {
    float lg[E];
#pragma unroll
    for (int e = 0; e < E; ++e) lg[e] = acc[e] + gb[e];
    int i0 = 0; float v0 = lg[0];
#pragma unroll
    for (int e = 1; e < E; ++e) { if (lg[e] > v0) { v0 = lg[e]; i0 = e; } }
    int i1 = -1; float v1 = -1e30f;
#pragma unroll
    for (int e = 0; e < E; ++e) { if (e != i0 && lg[e] > v1) { v1 = lg[e]; i1 = e; } }
    float e1 = __expf(v1 - v0);
    float inv = 1.f / (1.f + e1);
    sIdx[wv] = i0 | (i1 << 16);
    sW[wv] = make_float2(inv, e1 * inv);
  }
  if (tid < E) hist[tid] = 0;
  __syncthreads();

  if (tid == 0) {
#pragma unroll
    for (int w4 = 0; w4 < 4; ++w4) {
      int p = sIdx[w4];
      rofs[w4][0] = hist[p & 0xFFFF]++;
      rofs[w4][1] = hist[p >> 16]++;
    }
  }
  __syncthreads();
  if (tid < E) base[tid] = hist[tid] ? atomicAdd(&cnt[tid], hist[tid]) : 0;
  __syncthreads();

  if (tid == 0) {
#pragma unroll
    for (int w4 = 0; w4 < 4; ++w4) {
      int p = sIdx[w4];
      int tk = blockIdx.x * 4 + w4;
      int e0 = p & 0xFFFF, e1 = p >> 16;
      int s0 = base[e0] + rofs[w4][0];
      list[e0 * NTOK + s0] = tk;                         // rank 0
      wlist[e0 * NTOK + s0] = sW[w4].x;
      int s1 = base[e1] + rofs[w4][1];
      list[e1 * NTOK + s1] = tk | 0x80000000;            // rank 1
      wlist[e1 * NTOK + s1] = sW[w4].y;
    }
  }
}

// Grouped GEMM v8: BM=128,BN=64,BK=32, DOUBLE-BUFFERED at 24KB total LDS
// (6 blocks/CU retained) + expert->XCD pinning (e = bx%8; B panel 2MB
// L2-resident, FETCH 34MB verified R8) + packed-f16 epilogue (no atomics).
// Rows are 32 elem = 64B = 4 granules(16B). Swizzle: LDS slot s of row r
// holds global granule s ^ (r&3); staging lane l -> row l>>2, slot l&3,
// source granule (l&3)^((l>>2)&3) (inst base rows are %16==0 so
// (l>>2)&3 == r&3). Read: granule q of row (..+c) at slot q^(c&3) ->
// bank-uniform (8 accesses/bank, enumerated).
// One barrier/iter; prefetch slack = 1 iter (~8 MFMA + 6 ds_read) > L2 hit
// latency. 32 iters x 1 barrier = same barrier count as v6b's 16 x 2.
__global__ __launch_bounds__(256) void moe_gemm_kernel(
    const ushort* __restrict__ Db, const ushort* __restrict__ Wb,
    const float* __restrict__ eb, const int* __restrict__ cnt,
    const int* __restrict__ list, const float* __restrict__ wlist,
    float* __restrict__ out) {
  // bx = (mt*16 + nt)*8 + e : e fast (XCD-pinned), mt slowest (A-slice hot)
  const int bx = blockIdx.x;
  const int e  = bx & 7;
  const int mn = bx >> 3;
  const int mt = mn >> 4;
  const int nt = mn & 15;
  const int M  = cnt[e];
  const int m0 = mt * BM;
  if (m0 >= M) return;
  const int n0 = nt * BN;

  __shared__ ushort As[2 * ABUF];  // 16 KB
  __shared__ ushort Bs[2 * BBUF];  // 8 KB

  const int tid = threadIdx.x;
  const int wv = tid >> 6;
  const int lane = tid & 63;
  const int wm = wv >> 1;   // 0..1 : 64 rows
  const int wn = wv & 1;    // 0..1 : 32 cols
  const int c = lane & 15;
  const int q = lane >> 4;

  const int* listE = list + e * NTOK;

  // Staging: each inst covers 16 rows x 4 granules (64 lanes x 16B = 1KB).
  const int rl = lane >> 2;            // 0..15 local row
  const int sl = lane & 3;             // LDS slot
  const int gs = sl ^ (rl & 3);        // swizzled source granule
  const ushort* aptr[2];
  ushort* alds[2];
#pragma unroll
  for (int p = 0; p < 2; ++p) {
    int r = m0 + wv * 32 + p * 16 + rl;
    int tok = listE[r < M ? r : m0] & 0x7FFFFFFF;   // clamp padded rows
    aptr[p] = Db + (size_t)tok * D + gs * 8;
    alds[p] = &As[(wv * 32 + p * 16) * BK];
  }
  const ushort* WbE = Wb + ((size_t)e << 20);
  const int brow = n0 + wv * 16 + rl;
  const ushort* bptr = WbE + (size_t)brow * D + gs * 8;
  ushort* blds = &Bs[(wv * 16) * BK];

  f32x4 acc[4][2];
#pragma unroll
  for (int i = 0; i < 4; ++i)
#pragma unroll
    for (int j = 0; j < 2; ++j)
      acc[i][j] = (f32x4){0.f, 0.f, 0.f, 0.f};

  // Prologue: stage K-step 0 into buffer 0.
#pragma unroll
  for (int p = 0; p < 2; ++p)
    __builtin_amdgcn_global_load_lds(
        (const __attribute__((address_space(1))) void*)(aptr[p]),
        (__attribute__((address_space(3))) void*)(alds[p]), 16, 0, 0);
  __builtin_amdgcn_global_load_lds(
      (const __attribute__((address_space(1))) void*)(bptr),
      (__attribute__((address_space(3))) void*)(blds), 16, 0, 0);
  __syncthreads();

  const int swr = (q ^ (c & 3)) * 8;   // read slot offset (elements)

  for (int kt = 0; kt < NKT; ++kt) {
    const int cur = kt & 1;
    if (kt < NKT - 1) {
      const int nx = cur ^ 1;
      const int kk = (kt + 1) * BK;
#pragma unroll
      for (int p = 0; p < 2; ++p)
        __builtin_amdgcn_global_load_lds(
            (const __attribute__((address_space(1))) void*)(aptr[p] + kk),
            (__attribute__((address_space(3))) void*)(alds[p] + nx * ABUF), 16, 0, 0);
      __builtin_amdgcn_global_load_lds(
          (const __attribute__((address_space(1))) void*)(bptr + kk),
          (__attribute__((address_space(3))) void*)(blds + nx * BBUF), 16, 0, 0);
    }

    const ushort* Ab = As + cur * ABUF;
    const ushort* Bb = Bs + cur * BBUF;
    short8 a[4], b[2];
#pragma unroll
    for (int i = 0; i < 4; ++i)
      a[i] = *(const short8*)&Ab[(wm * 64 + i * 16 + c) * BK + swr];
#pragma unroll
    for (int j = 0; j < 2; ++j)
      b[j] = *(const short8*)&Bb[(wn * 32 + j * 16 + c) * BK + swr];
#pragma unroll
    for (int i = 0; i < 4; ++i)
#pragma unroll
      for (int j = 0; j < 2; ++j)
        acc[i][j] = __builtin_amdgcn_mfma_f32_16x16x32_bf16(a[i], b[j], acc[i][j], 0, 0, 0);

    // One barrier/iter: drains this iter's prefetch (hidden under compute,
    // L2-hit latency) and protects buf[cur] for next iter's overwrite.
    __syncthreads();
  }

  // Epilogue: C/D layout col=lane&15, row=(lane>>4)*4+reg.
  // Store f16 contribution into rank's half of out word. No atomics.
  float bias[2];
#pragma unroll
  for (int j = 0; j < 2; ++j)
    bias[j] = eb[e * D + n0 + wn * 32 + j * 16 + c];
  const float* wlE = wlist + e * NTOK;
  ushort* outh = (ushort*)out;
#pragma unroll
  for (int i = 0; i < 4; ++i) {
#pragma unroll
    for (int r = 0; r < 4; ++r) {
      int m = m0 + wm * 64 + i * 16 + q * 4 + r;
      if (m < M) {
        int en = listE[m];
        int tok = en & 0x7FFFFFFF;
        int rank = ((unsigned)en) >> 31;
        float w = wlE[m];
        size_t bi = ((size_t)tok * D + n0 + wn * 32 + c) * 2 + rank;
#pragma unroll
        for (int j = 0; j < 2; ++j)
          outh[bi + j * 32] = f2h((acc[i][j][r] + bias[j]) * w);
      }
    }
  }
}

// Sum the two packed f16 halves of each out word -> f32, in place.
#define NC4 2097152   // NTOK*D/4
__global__ __launch_bounds__(256) void combine_kernel(float* __restrict__ out) {
  int i = blockIdx.x * 256 + threadIdx.x;
  uint4 v = ((const uint4*)out)[i];
  float4 r;
  r.x = h2f((ushort)(v.x & 0xFFFF)) + h2f((ushort)(v.x >> 16));
  r.y = h2f((ushort)(v.y & 0xFFFF)) + h2f((ushort)(v.y >> 16));
  r.z = h2f((ushort)(v.z & 0xFFFF)) + h2f((ushort)(v.z >> 16));
  r.w = h2f((ushort)(v.w & 0xFFFF)) + h2f((ushort)(v.w >> 16));
  ((float4*)out)[i] = r;
}

extern "C" void kernel_launch(void* const* d_in, const int* in_sizes, int n_in,
                              void* d_out, int out_size, void* d_ws, size_t ws_size,
                              hipStream_t stream) {
  const float* input_feat = (const float*)d_in[0];
  const float* delta      = (const float*)d_in[1];
  const float* gate_W     = (const float*)d_in[2];
  const float* gate_b     = (const float*)d_in[3];
  const float* expert_W   = (const float*)d_in[4];
  const float* expert_b   = (const float*)d_in[5];
  float* out = (float*)d_out;

  // ws: Wb 16MiB | Db 16MiB | cnt | list | wlist   (~33.05 MB total)
  char* ws = (char*)d_ws;
  ushort* Wb    = (ushort*)ws;
  ushort* Db    = (ushort*)(ws + 16777216);
  char*   meta  = ws + 2 * 16777216;
  int*    cnt   = (int*)meta;
  int*    list  = (int*)(meta + 256);
  float*  wlist = (float*)(meta + 256 + NTOK * E * 4);

  convert_kernel<<<(NW4 + ND4) / 256, 256, 0, stream>>>(expert_W, delta, Wb, Db, cnt);
  gatebin_kernel<<<NTOK / 4, 256, 0, stream>>>(input_feat, gate_W, gate_b, cnt, list, wlist);
  moe_gemm_kernel<<<GEMM_GRID, 256, 0, stream>>>(
      Db, Wb, expert_b, cnt, list, wlist, out);
  combine_kernel<<<NC4 / 256, 256, 0, stream>>>(out);
}

// Round 11
// 226.052 us; speedup vs baseline: 1.0719x; 1.0719x over previous
//
// v9: GEMM + combine byte-identical to v6b (verified: GEMM 61.5us, conflicts 0,
// FETCH 34MB). Dispatch-count cut 4->3 kernels: convert+gatebin fused into
// prep_kernel (roles by blockIdx; mutually independent), cnt zeroed by a
// 32B hipMemsetAsync before it (stream-ordered, capture-legal).
// Theory under test: ~115us total-minus-kernel-sum gap ~= 29us/dispatch.
#include <hip/hip_runtime.h>
#include <hip/hip_fp16.h>
#include <stdint.h>

#define NTOK 8192   // B*T
#define D 1024
#define E 8
#define BM 128
#define BN 64
#define BK 64
#define GEMM_GRID ((NTOK / BM) * (D / BN) * E)   // 8192

typedef __attribute__((ext_vector_type(8))) short short8;
typedef __attribute__((ext_vector_type(4))) float f32x4;

// fp32 -> bf16 bits, round-to-nearest-even
__device__ __forceinline__ ushort f2bf(float f) {
  uint32_t x = __float_as_uint(f);
  x += 0x7FFFu + ((x >> 16) & 1u);
  return (ushort)(x >> 16);
}

__device__ __forceinline__ ushort f2h(float f) {
  union { __half h; ushort u; } cv;
  cv.h = __float2half(f);
  return cv.u;
}
__device__ __forceinline__ float h2f(ushort u) {
  union { __half h; ushort u; } cv;
  cv.u = u;
  return __half2float(cv.h);
}

#define NW4 2097152   // E*D*D/4
#define ND4 2097152   // NTOK*D/4
#define CONV_BLOCKS ((NW4 + ND4) / 256)   // 16384
#define GATE_BLOCKS (NTOK / 4)            // 2048
#define PREP_GRID (CONV_BLOCKS + GATE_BLOCKS)

// Fused prep: blocks [0, CONV_BLOCKS) convert expert_W/delta -> bf16;
// blocks [CONV_BLOCKS, ..) run gate top-2 softmax + counting-append bin
// (cnt pre-zeroed by the memset dispatch; roles are data-independent so
// block execution order is irrelevant). List entry: rank in bit 31
// (rank0 -> low f16 half of out word, rank1 -> high half).
__global__ __launch_bounds__(256) void prep_kernel(
    const float* __restrict__ expert_W, const float* __restrict__ delta,
    const float* __restrict__ x, const float* __restrict__ gW,
    const float* __restrict__ gb, ushort* __restrict__ Wb,
    ushort* __restrict__ Db, int* __restrict__ cnt,
    int* __restrict__ list, float* __restrict__ wlist) {
  const int bx = blockIdx.x;
  const int tid = threadIdx.x;

  if (bx < CONV_BLOCKS) {
    int i = bx * 256 + tid;
    if (i < NW4) {
      float4 v = ((const float4*)expert_W)[i];
      ushort4 u; u.x = f2bf(v.x); u.y = f2bf(v.y); u.z = f2bf(v.z); u.w = f2bf(v.w);
      ((ushort4*)Wb)[i] = u;
    } else {
      int j = i - NW4;
      float4 v = ((const float4*)delta)[j];
      ushort4 u; u.x = f2bf(v.x); u.y = f2bf(v.y); u.z = f2bf(v.z); u.w = f2bf(v.w);
      ((ushort4*)Db)[j] = u;
    }
    return;
  }

  // Gate + bin role: 4 tokens/block, one per wave.
  const int gbx = bx - CONV_BLOCKS;
  const int wv = tid >> 6;
  const int lane = tid & 63;
  const int t = gbx * 4 + wv;

  const float4* xr = (const float4*)(x + (size_t)t * D) + lane * 4;
  float acc[E];
#pragma unroll
  for (int e = 0; e < E; ++e) acc[e] = 0.f;
#pragma unroll
  for (int qq = 0; qq < 4; ++qq) {
    float4 xv = xr[qq];
#pragma unroll
    for (int e = 0; e < E; ++e) {
      float4 wvv = ((const float4*)(gW + e * D))[lane * 4 + qq];
      acc[e] += xv.x * wvv.x + xv.y * wvv.y + xv.z * wvv.z + xv.w * wvv.w;
    }
  }
#pragma unroll
  for (int e = 0; e < E; ++e) {
    float v = acc[e];
#pragma unroll
    for (int off = 32; off > 0; off >>= 1) v += __shfl_xor(v, off, 64);
    acc[e] = v;
  }

  __shared__ int sIdx[4];      // packed i0 | i1<<16 per wave
  __shared__ float2 sW[4];
  __shared__ int hist[E];
  __shared__ int base[E];
  __shared__ int rofs[4][2];   // within-block rank offsets

  if (lane == 0) {
    float lg[E];
#pragma unroll
    for (int e = 0; e < E; ++e) lg[e] = acc[e] + gb[e];
    int i0 = 0; float v0 = lg[0];
#pragma unroll
    for (int e = 1; e < E; ++e) { if (lg[e] > v0) { v0 = lg[e]; i0 = e; } }
    int i1 = -1; float v1 = -1e30f;
#pragma unroll
    for (int e = 0; e < E; ++e) { if (e != i0 && lg[e] > v1) { v1 = lg[e]; i1 = e; } }
    float e1 = __expf(v1 - v0);
    float inv = 1.f / (1.f + e1);
    sIdx[wv] = i0 | (i1 << 16);
    sW[wv] = make_float2(inv, e1 * inv);
  }
  if (tid < E) hist[tid] = 0;
  __syncthreads();

  if (tid == 0) {
#pragma unroll
    for (int w4 = 0; w4 < 4; ++w4) {
      int p = sIdx[w4];
      rofs[w4][0] = hist[p & 0xFFFF]++;
      rofs[w4][1] = hist[p >> 16]++;
    }
  }
  __syncthreads();
  if (tid < E) base[tid] = hist[tid] ? atomicAdd(&cnt[tid], hist[tid]) : 0;
  __syncthreads();

  if (tid == 0) {
#pragma unroll
    for (int w4 = 0; w4 < 4; ++w4) {
      int p = sIdx[w4];
      int tk = gbx * 4 + w4;
      int e0 = p & 0xFFFF, e1 = p >> 16;
      int s0 = base[e0] + rofs[w4][0];
      list[e0 * NTOK + s0] = tk;                         // rank 0
      wlist[e0 * NTOK + s0] = sW[w4].x;
      int s1 = base[e1] + rofs[w4][1];
      list[e1 * NTOK + s1] = tk | 0x80000000;            // rank 1
      wlist[e1 * NTOK + s1] = sW[w4].y;
    }
  }
}

// Grouped GEMM (byte-identical to v6b): 1-phase, BM=128,BN=64,BK=64, 24KB
// LDS, expert->XCD pinning (e = bx%8 -> B panel 2MB L2-resident per XCD;
// FETCH 34MB verified R8), packed-f16 epilogue (disjoint bytes, no atomics).
// LDS layout: slot (row, s) holds global granule s ^ (row&7) (granule=16B).
__global__ __launch_bounds__(256) void moe_gemm_kernel(
    const ushort* __restrict__ Db, const ushort* __restrict__ Wb,
    const float* __restrict__ eb, const int* __restrict__ cnt,
    const int* __restrict__ list, const float* __restrict__ wlist,
    float* __restrict__ out) {
  // bx = (mt*16 + nt)*8 + e : e fast (XCD-pinned), mt slowest (A-slice hot)
  const int bx = blockIdx.x;
  const int e  = bx & 7;
  const int mn = bx >> 3;
  const int mt = mn >> 4;
  const int nt = mn & 15;
  const int M  = cnt[e];
  const int m0 = mt * BM;
  if (m0 >= M) return;
  const int n0 = nt * BN;

  __shared__ ushort As[BM * BK];  // 16 KB
  __shared__ ushort Bs[BN * BK];  // 8 KB

  const int tid = threadIdx.x;
  const int wv = tid >> 6;
  const int lane = tid & 63;
  const int wm = wv >> 1;   // 0..1 : 64 rows
  const int wn = wv & 1;    // 0..1 : 32 cols
  const int c = lane & 15;
  const int q = lane >> 4;

  const int* listE = list + e * NTOK;

  // Staging: inst covers 8 rows x 8 granules; lane l -> row +(l>>3), slot l&7,
  // fetches global granule (l&7)^(l>>3)  (row&7 == l>>3 since bases are %8==0).
  const int rloc = lane >> 3;                 // 0..7
  const int gglob = (lane & 7) ^ rloc;        // swizzled source granule
  const ushort* aptr[4];
  ushort* alds[4];
#pragma unroll
  for (int p = 0; p < 4; ++p) {
    int r = m0 + wv * 32 + p * 8 + rloc;
    int tok = listE[r < M ? r : m0] & 0x7FFFFFFF;   // clamp padded rows
    aptr[p] = Db + (size_t)tok * D + gglob * 8;
    alds[p] = &As[(wv * 32 + p * 8) * BK];
  }
  const ushort* WbE = Wb + ((size_t)e << 20);
  const ushort* bptr[2];
  ushort* blds[2];
#pragma unroll
  for (int sub = 0; sub < 2; ++sub) {
    int row = n0 + wv * 16 + sub * 8 + rloc;
    bptr[sub] = WbE + (size_t)row * D + gglob * 8;
    blds[sub] = &Bs[(wv * 16 + sub * 8) * BK];
  }

  f32x4 acc[4][2];
#pragma unroll
  for (int i = 0; i < 4; ++i)
#pragma unroll
    for (int j = 0; j < 2; ++j)
      acc[i][j] = (f32x4){0.f, 0.f, 0.f, 0.f};

  for (int k0 = 0; k0 < D; k0 += BK) {
#pragma unroll
    for (int p = 0; p < 4; ++p)
      __builtin_amdgcn_global_load_lds(
          (const __attribute__((address_space(1))) void*)(aptr[p] + k0),
          (__attribute__((address_space(3))) void*)alds[p], 16, 0, 0);
#pragma unroll
    for (int sub = 0; sub < 2; ++sub)
      __builtin_amdgcn_global_load_lds(
          (const __attribute__((address_space(1))) void*)(bptr[sub] + k0),
          (__attribute__((address_space(3))) void*)blds[sub], 16, 0, 0);
    __syncthreads();

#pragma unroll
    for (int s = 0; s < 2; ++s) {
      // granule g = s*4+q; swizzled LDS slot = g ^ (row&7), row&7 = c&7
      const int sw = (((s * 4 + q) ^ (c & 7)) * 8);
      short8 a[4], b[2];
#pragma unroll
      for (int i = 0; i < 4; ++i)
        a[i] = *(const short8*)&As[(wm * 64 + i * 16 + c) * BK + sw];
#pragma unroll
      for (int j = 0; j < 2; ++j)
        b[j] = *(const short8*)&Bs[(wn * 32 + j * 16 + c) * BK + sw];
#pragma unroll
      for (int i = 0; i < 4; ++i)
#pragma unroll
        for (int j = 0; j < 2; ++j)
          acc[i][j] = __builtin_amdgcn_mfma_f32_16x16x32_bf16(a[i], b[j], acc[i][j], 0, 0, 0);
    }
    __syncthreads();
  }

  // Epilogue: C/D layout col=lane&15, row=(lane>>4)*4+reg.
  // Store f16 contribution into rank's half of out word. No atomics.
  float bias[2];
#pragma unroll
  for (int j = 0; j < 2; ++j)
    bias[j] = eb[e * D + n0 + wn * 32 + j * 16 + c];
  const float* wlE = wlist + e * NTOK;
  ushort* outh = (ushort*)out;
#pragma unroll
  for (int i = 0; i < 4; ++i) {
#pragma unroll
    for (int r = 0; r < 4; ++r) {
      int m = m0 + wm * 64 + i * 16 + q * 4 + r;
      if (m < M) {
        int en = listE[m];
        int tok = en & 0x7FFFFFFF;
        int rank = ((unsigned)en) >> 31;
        float w = wlE[m];
        size_t bi = ((size_t)tok * D + n0 + wn * 32 + c) * 2 + rank;
#pragma unroll
        for (int j = 0; j < 2; ++j)
          outh[bi + j * 32] = f2h((acc[i][j][r] + bias[j]) * w);
      }
    }
  }
}

// Sum the two packed f16 halves of each out word -> f32, in place.
#define NC4 2097152   // NTOK*D/4
__global__ __launch_bounds__(256) void combine_kernel(float* __restrict__ out) {
  int i = blockIdx.x * 256 + threadIdx.x;
  uint4 v = ((const uint4*)out)[i];
  float4 r;
  r.x = h2f((ushort)(v.x & 0xFFFF)) + h2f((ushort)(v.x >> 16));
  r.y = h2f((ushort)(v.y & 0xFFFF)) + h2f((ushort)(v.y >> 16));
  r.z = h2f((ushort)(v.z & 0xFFFF)) + h2f((ushort)(v.z >> 16));
  r.w = h2f((ushort)(v.w & 0xFFFF)) + h2f((ushort)(v.w >> 16));
  ((float4*)out)[i] = r;
}

extern "C" void kernel_launch(void* const* d_in, const int* in_sizes, int n_in,
                              void* d_out, int out_size, void* d_ws, size_t ws_size,
                              hipStream_t stream) {
  const float* input_feat = (const float*)d_in[0];
  const float* delta      = (const float*)d_in[1];
  const float* gate_W     = (const float*)d_in[2];
  const float* gate_b     = (const float*)d_in[3];
  const float* expert_W   = (const float*)d_in[4];
  const float* expert_b   = (const float*)d_in[5];
  float* out = (float*)d_out;

  // ws: Wb 16MiB | Db 16MiB | cnt | list | wlist   (~33.05 MB total)
  char* ws = (char*)d_ws;
  ushort* Wb    = (ushort*)ws;
  ushort* Db    = (ushort*)(ws + 16777216);
  char*   meta  = ws + 2 * 16777216;
  int*    cnt   = (int*)meta;
  int*    list  = (int*)(meta + 256);
  float*  wlist = (float*)(meta + 256 + NTOK * E * 4);

  // cnt=0 must precede prep's atomics; stream-ordered, graph-capture-legal.
  hipMemsetAsync(cnt, 0, E * sizeof(int), stream);
  prep_kernel<<<PREP_GRID, 256, 0, stream>>>(
      expert_W, delta, input_feat, gate_W, gate_b, Wb, Db, cnt, list, wlist);
  moe_gemm_kernel<<<GEMM_GRID, 256, 0, stream>>>(
      Db, Wb, expert_b, cnt, list, wlist, out);
  combine_kernel<<<NC4 / 256, 256, 0, stream>>>(out);
}